// Round 2
// baseline (106.193 us; speedup 1.0000x reference)
//
#include <hip/hip_runtime.h>
#include <hip/hip_bf16.h>

#define CC 64
#define NN 4096   // H*W
#define MM 1024   // pooled pixels

typedef __attribute__((ext_vector_type(4))) short s4b;      // 4 bf16 = 2 VGPRs
typedef __attribute__((ext_vector_type(8))) short s8b;      // 8 bf16 = 4 VGPRs
typedef __attribute__((ext_vector_type(4))) float float4v;  // MFMA C/D frag

__device__ inline unsigned short f2bf(float f) {
    union { float f; unsigned u; } v; v.f = f;
    unsigned r = v.u + 0x7fff + ((v.u >> 16) & 1);   // RNE
    return (unsigned short)(r >> 16);
}

__device__ inline float4v mfma16(s4b a, s4b b, float4v c) {
#if __has_builtin(__builtin_amdgcn_mfma_f32_16x16x16bf16_1k)
    return __builtin_amdgcn_mfma_f32_16x16x16bf16_1k(a, b, c, 0, 0, 0);
#else
    float4v d;
    asm volatile("v_mfma_f32_16x16x16_bf16 %0, %1, %2, %3"
                 : "=v"(d) : "v"(a), "v"(b), "v"(c));
    return d;
#endif
}

__device__ inline float4v mfma32(s8b a, s8b b, float4v c) {
#if __has_builtin(__builtin_amdgcn_mfma_f32_16x16x32_bf16)
    return __builtin_amdgcn_mfma_f32_16x16x32_bf16(a, b, c, 0, 0, 0);
#else
    float4v d;
    asm volatile("v_mfma_f32_16x16x32_bf16 %0, %1, %2, %3"
                 : "=v"(d) : "v"(a), "v"(b), "v"(c));
    return d;
#endif
}

// ---------------------------------------------------------------------------
// prep_kernel v3: LDS-issue fix. Each thread = 2 horizontal pixels (float2)
// x 16 channels (lane>>4 c-split); weight broadcast reads amortize over 2 px
// (384 -> 192 b128/px) and the c-reduction is shfl_xor(16/32), not LDS.
// Weights staged [h2][16c][48j] pitch 776 words so the 4 h2-group broadcast
// addresses land on disjoint bank quartets (8*h2 offset). Only the vertical
// 2x2-pool max goes through LDS (horizontal max is in-thread).
// Block 256 thr = 4 waves: wave w = row (w>>1), cp-half (w&1); lanes =
// 16 slots x 4 c-groups. Covers 2 rows x 64 cols = 128 px. Grid (32,16).
// ---------------------------------------------------------------------------
__global__ __launch_bounds__(256) void prep_kernel(
    const float* __restrict__ x,
    const float* __restrict__ Wth,
    const float* __restrict__ Wph,
    const float* __restrict__ Wg,
    unsigned short* __restrict__ thT,
    unsigned short* __restrict__ phiP,
    unsigned short* __restrict__ gP)
{
    __shared__ __align__(16) float wtg[4 * 776];   // 12.4 KB
    __shared__ __align__(16) float pbuf[32 * 40];  // 5 KB (row-1 hmax)

    const int tid  = threadIdx.x;
    const int b    = blockIdx.y;
    const int hp   = blockIdx.x;        // rows 2hp, 2hp+1
    const int lane = tid & 63;
    const int w    = tid >> 6;          // wave 0..3
    const int h2   = lane >> 4;         // c-group 0..3 (16 ch each)
    const int sl   = lane & 15;
    const int row  = w >> 1;            // 0..1
    const int cp   = (w & 1) * 16 + sl; // col-pair 0..31

    for (int idx = tid; idx < 3072; idx += 256) {
        const int c = idx / 48, j = idx % 48;
        float v;
        if (j < 8)       v = Wth[j * 64 + c];
        else if (j < 16) v = Wph[(j - 8) * 64 + c];
        else             v = Wg[(j - 16) * 64 + c];
        wtg[(c >> 4) * 776 + (c & 15) * 48 + j] = v;
    }
    __syncthreads();

    const int n = (2 * hp + row) * 64 + 2 * cp;
    const float* xb = x + (size_t)b * CC * NN + (size_t)(h2 * 16) * NN + n;

    float2 xv[16];
#pragma unroll
    for (int u = 0; u < 16; ++u) xv[u] = *(const float2*)&xb[(size_t)u * NN];

    float ax[48], ay[48];
#pragma unroll
    for (int j = 0; j < 48; ++j) { ax[j] = 0.f; ay[j] = 0.f; }

    const float* wr0 = &wtg[h2 * 776];
#pragma unroll
    for (int u = 0; u < 16; ++u) {
        const float* wrow = wr0 + u * 48;
        const float2 xu = xv[u];
#pragma unroll
        for (int j = 0; j < 48; ++j) {
            const float wv_ = wrow[j];
            ax[j] = fmaf(wv_, xu.x, ax[j]);
            ay[j] = fmaf(wv_, xu.y, ay[j]);
        }
    }

    // c-reduction across the 4 h2 groups (lane bits 4,5)
#pragma unroll
    for (int j = 0; j < 48; ++j) {
        ax[j] += __shfl_xor(ax[j], 16, 64);
        ay[j] += __shfl_xor(ay[j], 16, 64);
        ax[j] += __shfl_xor(ax[j], 32, 64);
        ay[j] += __shfl_xor(ay[j], 32, 64);
    }

    // theta out (h2==0 lanes): 2 px x 8 bf16 = 32 B contiguous
    if (h2 == 0) {
        union { unsigned short s[16]; uint4 v[2]; } pk;
#pragma unroll
        for (int j = 0; j < 8; ++j) {
            pk.s[j]     = f2bf(ax[j] * 1.44269504f);
            pk.s[8 + j] = f2bf(ay[j] * 1.44269504f);
        }
        uint4* dst = (uint4*)&thT[((size_t)b * NN + n) * 8];
        dst[0] = pk.v[0]; dst[1] = pk.v[1];
    }

    // horizontal max in-thread (phi/g channels)
    float hm[40];
#pragma unroll
    for (int j = 0; j < 40; ++j) hm[j] = fmaxf(ax[8 + j], ay[8 + j]);

    if (row == 1 && h2 == 1) {
#pragma unroll
        for (int j4 = 0; j4 < 10; ++j4) {
            float4 t;
            t.x = hm[j4 * 4 + 0]; t.y = hm[j4 * 4 + 1];
            t.z = hm[j4 * 4 + 2]; t.w = hm[j4 * 4 + 3];
            *(float4*)&pbuf[cp * 40 + j4 * 4] = t;
        }
    }
    __syncthreads();

    if (row == 0 && h2 >= 2) {
        const int m = hp * 32 + cp;
        if (h2 == 2) {
            union { unsigned short s[8]; uint4 v; } pk;
#pragma unroll
            for (int j = 0; j < 8; ++j)
                pk.s[j] = f2bf(fmaxf(hm[j], pbuf[cp * 40 + j]));
            *(uint4*)&phiP[((size_t)b * MM + m) * 8] = pk.v;
#pragma unroll
            for (int j = 8; j < 24; ++j)
                gP[((size_t)b * 32 + (j - 8)) * MM + m] =
                    f2bf(fmaxf(hm[j], pbuf[cp * 40 + j]));
        } else {
#pragma unroll
            for (int j = 24; j < 40; ++j)
                gP[((size_t)b * 32 + (j - 8)) * MM + m] =
                    f2bf(fmaxf(hm[j], pbuf[cp * 40 + j]));
        }
    }
}

// ---------------------------------------------------------------------------
// attn_mfma v5: 2 query-tiles per wave. Block = 128 queries (4 waves x 2x16),
// grid (32,16). phi A-frags and g B-frags are query-independent, so each LDS
// read now feeds 4 score MFMAs + 4 PV MFMAs (main-loop LDS issue per CU
// halves; staging traffic also halves). Layouts identical to v4.
// ---------------------------------------------------------------------------
__global__ __launch_bounds__(256) void attn_mfma(
    const unsigned short* __restrict__ thT,   // [B][N][8]
    const unsigned short* __restrict__ phiP,  // [B][M][8]
    const unsigned short* __restrict__ gP,    // [B][32][M]
    const float* __restrict__ x,
    const float* __restrict__ Wa,             // [64][32]
    const float* __restrict__ sigma,
    float* __restrict__ out)
{
    constexpr int GP = 264;   // g_s pitch (bf16): 528 B = 33x16 -> aligned rows
    constexpr int OBP = 40;   // obb pitch (bf16): 80 B = 5x16 -> aligned rows

    __shared__ __align__(16) union {
        struct {
            unsigned short phi[256 * 8 + 16];  // pad: slot-255 quad2/3 overread
            unsigned short g[32 * GP];
        } m;                                    // 24.6 KB
        unsigned short obb[128 * OBP];          // 10.2 KB (epilogue)
    } sh;

    const int tid  = threadIdx.x;
    const int lane = tid & 63;
    const int wv   = tid >> 6;
    const int c15  = lane & 15;     // score D col = query; PV D col = gi
    const int quad = lane >> 4;
    const int b    = blockIdx.y;
    const int n0   = blockIdx.x * 128;

    // Wa A-frag in registers: A[m=c15 -> o=wv*16+c15][k=quad*8+j -> gi]
    union { unsigned short s[8]; s8b v; } wfrag;
    {
        const float* wr = Wa + (wv * 16 + c15) * 32 + quad * 8;
        const float4 w0 = *(const float4*)wr;
        const float4 w1 = *(const float4*)(wr + 4);
        wfrag.s[0] = f2bf(w0.x); wfrag.s[1] = f2bf(w0.y);
        wfrag.s[2] = f2bf(w0.z); wfrag.s[3] = f2bf(w0.w);
        wfrag.s[4] = f2bf(w1.x); wfrag.s[5] = f2bf(w1.y);
        wfrag.s[6] = f2bf(w1.z); wfrag.s[7] = f2bf(w1.w);
    }

    // theta B-frags for both query tiles: B[k=quad*4+j][n=q]; quads 0,1 real
    s4b zero4 = {0, 0, 0, 0};
    s4b bthA = zero4, bthB = zero4;
    if (quad < 2) {
        union { uint2 u; s4b s; } t;
        t.u = *(const uint2*)&thT[((size_t)b * NN + n0 + wv * 32 + c15) * 8 + quad * 4];
        bthA = t.s;
        t.u = *(const uint2*)&thT[((size_t)b * NN + n0 + wv * 32 + 16 + c15) * 8 + quad * 4];
        bthB = t.s;
    }

    float4v accA0 = {0.f, 0.f, 0.f, 0.f};
    float4v accA1 = {0.f, 0.f, 0.f, 0.f};
    float4v accB0 = {0.f, 0.f, 0.f, 0.f};
    float4v accB1 = {0.f, 0.f, 0.f, 0.f};
    float zaccA = 0.f, zaccB = 0.f;

    for (int ch = 0; ch < 4; ++ch) {
        __syncthreads();
        // stage phi slot-permuted (+ zero the pad). key k = tid within chunk:
        // r=k&7, q3=(k>>3)&3 -> slot = (k&~31) | ((r>>2)<<4) | (q3<<2) | (r&3)
        {
            const int r  = tid & 7;
            const int q3 = (tid >> 3) & 3;
            const int slot = (tid & ~31) | ((r >> 2) << 4) | (q3 << 2) | (r & 3);
            *(uint4*)&sh.m.phi[slot * 8] =
                *(const uint4*)&phiP[((size_t)b * MM + ch * 256 + tid) * 8];
            if (tid < 2) {
                uint4 z4; z4.x = z4.y = z4.z = z4.w = 0u;
                *(uint4*)&sh.m.phi[256 * 8 + tid * 8] = z4;
            }
        }
        // stage g: 32 rows x 256 bf16 = 1024 uint4 (rows 16B-aligned), linear
#pragma unroll
        for (int it = 0; it < 4; ++it) {
            const int idx = tid + 256 * it;
            const int grow = idx >> 5, c32 = idx & 31;
            *(uint4*)&sh.m.g[grow * GP + c32 * 8] =
                *(const uint4*)&gP[((size_t)b * 32 + grow) * MM + ch * 256 + c32 * 8];
        }
        __syncthreads();

        const unsigned short* pA  = &sh.m.phi[c15 * 8 + quad * 4];
        const unsigned short* pg0 = &sh.m.g[c15 * GP + quad * 8];
        const unsigned short* pg1 = pg0 + 16 * GP;

#pragma unroll
        for (int g32 = 0; g32 < 8; ++g32) {
            // phi A-frags (query-independent): keys quad*8+0..3 / +4..7
            union { uint2 u; s4b s; } apA, apB;
            apA.u = *(const uint2*)&pA[g32 * 256];
            apB.u = *(const uint2*)&pA[g32 * 256 + 128];

            float4v cz = {0.f, 0.f, 0.f, 0.f};
            float4v sAlo = mfma16(apA.s, bthA, cz);   // D[key=quad*8+r][qA=c15]
            float4v sAhi = mfma16(apB.s, bthA, cz);   // keys +4..7
            float4v sBlo = mfma16(apA.s, bthB, cz);
            float4v sBhi = mfma16(apB.s, bthB, cz);

            union { float f; unsigned u; } a0, a1, a2, a3, b0, b1, b2, b3;
            a0.f = __builtin_amdgcn_exp2f(sAlo[0]);
            a1.f = __builtin_amdgcn_exp2f(sAlo[1]);
            a2.f = __builtin_amdgcn_exp2f(sAlo[2]);
            a3.f = __builtin_amdgcn_exp2f(sAlo[3]);
            b0.f = __builtin_amdgcn_exp2f(sAhi[0]);
            b1.f = __builtin_amdgcn_exp2f(sAhi[1]);
            b2.f = __builtin_amdgcn_exp2f(sAhi[2]);
            b3.f = __builtin_amdgcn_exp2f(sAhi[3]);
            zaccA += ((a0.f + a1.f) + (a2.f + a3.f)) +
                     ((b0.f + b1.f) + (b2.f + b3.f));
            union { uint4 u; s8b s; } paA;
            paA.u.x = __builtin_amdgcn_perm(a1.u, a0.u, 0x07060302u);
            paA.u.y = __builtin_amdgcn_perm(a3.u, a2.u, 0x07060302u);
            paA.u.z = __builtin_amdgcn_perm(b1.u, b0.u, 0x07060302u);
            paA.u.w = __builtin_amdgcn_perm(b3.u, b2.u, 0x07060302u);

            a0.f = __builtin_amdgcn_exp2f(sBlo[0]);
            a1.f = __builtin_amdgcn_exp2f(sBlo[1]);
            a2.f = __builtin_amdgcn_exp2f(sBlo[2]);
            a3.f = __builtin_amdgcn_exp2f(sBlo[3]);
            b0.f = __builtin_amdgcn_exp2f(sBhi[0]);
            b1.f = __builtin_amdgcn_exp2f(sBhi[1]);
            b2.f = __builtin_amdgcn_exp2f(sBhi[2]);
            b3.f = __builtin_amdgcn_exp2f(sBhi[3]);
            zaccB += ((a0.f + a1.f) + (a2.f + a3.f)) +
                     ((b0.f + b1.f) + (b2.f + b3.f));
            union { uint4 u; s8b s; } paB;
            paB.u.x = __builtin_amdgcn_perm(a1.u, a0.u, 0x07060302u);
            paB.u.y = __builtin_amdgcn_perm(a3.u, a2.u, 0x07060302u);
            paB.u.z = __builtin_amdgcn_perm(b1.u, b0.u, 0x07060302u);
            paB.u.w = __builtin_amdgcn_perm(b3.u, b2.u, 0x07060302u);

            // g B-frags (query-independent)
            union { uint4 u; s8b s; } bg0, bg1;
            bg0.u = *(const uint4*)&pg0[g32 * 32];
            bg1.u = *(const uint4*)&pg1[g32 * 32];

            accA0 = mfma32(paA.s, bg0.s, accA0);   // D[q=quad*4+r][gi=c15]
            accA1 = mfma32(paA.s, bg1.s, accA1);   // gi = c15+16
            accB0 = mfma32(paB.s, bg0.s, accB0);
            accB1 = mfma32(paB.s, bg1.s, accB1);
        }
    }

    // full Z per query at every lane (q = c15)
    float zA = zaccA, zB = zaccB;
    zA += __shfl_xor(zA, 16, 64);
    zA += __shfl_xor(zA, 32, 64);
    zB += __shfl_xor(zB, 16, 64);
    zB += __shfl_xor(zB, 32, 64);
    const float rzqA = __builtin_amdgcn_rcpf(zA);
    const float rzqB = __builtin_amdgcn_rcpf(zB);

    __syncthreads();   // main-loop LDS reads done before obb overwrites

    // obar -> bf16 LDS rows [q][gi], pitch 40 (80 B, 16B-aligned)
#pragma unroll
    for (int r = 0; r < 4; ++r) {
        const float rzA = __shfl(rzqA, quad * 4 + r, 64);
        const float rzB = __shfl(rzqB, quad * 4 + r, 64);
        const int qlA = wv * 32 + quad * 4 + r;
        const int qlB = qlA + 16;
        sh.obb[qlA * OBP + c15]      = f2bf(accA0[r] * rzA);
        sh.obb[qlA * OBP + 16 + c15] = f2bf(accA1[r] * rzA);
        sh.obb[qlB * OBP + c15]      = f2bf(accB0[r] * rzB);
        sh.obb[qlB * OBP + 16 + c15] = f2bf(accB1[r] * rzB);
    }
    __syncthreads();

    // epilogue: out[o][q] = x + sigma * Wa[o][:32] . obar[q][:32]
    // one x32 MFMA per 16-query tile: A = wfrag, B[k=gi=quad*8+j][n=q=c15]
    const float sg = sigma[0];
#pragma unroll
    for (int t = 0; t < 8; ++t) {
        union { uint4 u; s8b s; } bo;
        bo.u = *(const uint4*)&sh.obb[(t * 16 + c15) * OBP + quad * 8];
        float4v cz = {0.f, 0.f, 0.f, 0.f};
        float4v oc = mfma32(wfrag.v, bo.s, cz);   // D[o=wv*16+quad*4+r][q=c15]
#pragma unroll
        for (int r = 0; r < 4; ++r) {
            const size_t oi = ((size_t)b * CC + wv * 16 + quad * 4 + r) * NN
                              + n0 + t * 16 + c15;
            out[oi] = x[oi] + sg * oc[r];
        }
    }
}

extern "C" void kernel_launch(void* const* d_in, const int* in_sizes, int n_in,
                              void* d_out, int out_size, void* d_ws, size_t ws_size,
                              hipStream_t stream) {
    const float* x      = (const float*)d_in[0];
    const float* W_th   = (const float*)d_in[1];
    const float* W_ph   = (const float*)d_in[2];
    const float* W_g    = (const float*)d_in[3];
    const float* W_attn = (const float*)d_in[4];
    const float* sigma  = (const float*)d_in[5];
    float* out = (float*)d_out;

    const int B = 16;
    unsigned short* thT  = (unsigned short*)d_ws;              // B*N*8
    unsigned short* phiP = thT + (size_t)B * NN * 8;           // B*M*8
    unsigned short* gP   = phiP + (size_t)B * MM * 8;          // B*32*M

    prep_kernel<<<dim3(32, 16), 256, 0, stream>>>(x, W_th, W_ph, W_g,
                                                  thT, phiP, gP);
    attn_mfma<<<dim3(32, 16), 256, 0, stream>>>(thT, phiP, gP, x,
                                                W_attn, sigma, out);
}